// Round 10
// baseline (320.633 us; speedup 1.0000x reference)
//
#include <hip/hip_runtime.h>
#include <hip/hip_fp16.h>

#define Hh 1024
#define Ww 1024
#define PS 1040      // padded row stride (image at offset PO)
#define PO 8         // halo offset (>= T+1)
#define T 5          // fused iterations per launch (100 = 20 launches x 5)
#define TR 16        // tile rows per block
#define TC 32        // tile cols per block
#define RR 26        // region rows = TR + 2T
#define RC 42        // region cols = TC + 2T
#define XSH 44       // LDS row stride in px (half2 = 4B; EVEN -> uint2 aligned)
#define NPX (RR * RC)  // 1092 region pixels
#define NKS 9        // ceil(NPX / 128)

typedef unsigned int u32;

// packed per-pixel weights: 8 x fp16 in one 16B struct (w0..w7)
struct alignas(16) W8 { __half2 a, b, c, d; };

__device__ inline __half2 h2(u32 v) { return *(__half2*)&v; }
__device__ inline u32 u2(__half2 v) { return *(u32*)&v; }

// ---------------------------------------------------------------------------
// prep: Ypad (luma, zero halo), x0 = b as half2 (IQ if colored else 0, zero
// halo), x1 = 0, mask (isColored).
// ---------------------------------------------------------------------------
__global__ __launch_bounds__(256)
void prep_kernel(const float* __restrict__ gray, const float* __restrict__ app,
                 float* __restrict__ Ypad, u32* __restrict__ x0,
                 u32* __restrict__ x1, unsigned char* __restrict__ mask) {
    int px = blockIdx.x * 64 + threadIdx.x;
    int py = blockIdx.y * 4 + threadIdx.y;
    if (px >= PS || py >= PS) return;
    int p = py * PS + px;
    int i = py - PO, j = px - PO;
    float yv = 0.f;
    float2 bv = make_float2(0.f, 0.f);
    if (i >= 0 && i < Hh && j >= 0 && j < Ww) {
        int idx = i * Ww + j;
        const float s = 1.f / 255.f;
        float gr = gray[idx * 3 + 0] * s;
        float gg = gray[idx * 3 + 1] * s;
        float gb = gray[idx * 3 + 2] * s;
        float ar = app[idx * 3 + 0] * s;
        float ag = app[idx * 3 + 1] * s;
        float ab = app[idx * 3 + 2] * s;
        float diff = fabsf(gr - ar) + fabsf(gg - ag) + fabsf(gb - ab);
        bool colored = diff > 0.01f;
        yv = 0.3f * gr + 0.59f * gg + 0.11f * gb;
        float ay = 0.3f * ar + 0.59f * ag + 0.11f * ab;
        float ai = 0.74f * (ar - ay) - 0.27f * (ab - ay);
        float aq = 0.48f * (ar - ay) + 0.41f * (ab - ay);
        if (colored) bv = make_float2(ai, aq);
        mask[idx] = colored ? 1 : 0;
    }
    Ypad[p] = yv;
    __half2 h = __floats2half2_rn(bv.x, bv.y);
    x0[p] = u2(h);
    x1[p] = 0u;                 // half2(0,0)
}

// ---------------------------------------------------------------------------
// weights: per padded pixel, 8 normalized neighbor weights packed fp16 (16B).
// Outside the image: all zero. Colored pixel: all zero except sign bit on w0
// (-0.0h = "keep center").
// ---------------------------------------------------------------------------
__global__ __launch_bounds__(256)
void weights_kernel(const float* __restrict__ Ypad,
                    const unsigned char* __restrict__ mask,
                    W8* __restrict__ w) {
    int px = blockIdx.x * 64 + threadIdx.x;
    int py = blockIdx.y * 4 + threadIdx.y;
    if (px >= PS || py >= PS) return;
    int p = py * PS + px;
    int i = py - PO, j = px - PO;
    W8 out;
    out.a = __floats2half2_rn(0.f, 0.f);
    out.b = out.a; out.c = out.a; out.d = out.a;
    if (i >= 0 && i < Hh && j >= 0 && j < Ww) {
        float yc = Ypad[p];
        float yn[8];
        yn[0] = Ypad[p - PS - 1]; yn[1] = Ypad[p - PS]; yn[2] = Ypad[p - PS + 1];
        yn[3] = Ypad[p - 1];                            yn[4] = Ypad[p + 1];
        yn[5] = Ypad[p + PS - 1]; yn[6] = Ypad[p + PS]; yn[7] = Ypad[p + PS + 1];
        float vt = (i > 0) ? 1.f : 0.f;
        float vb = (i < Hh - 1) ? 1.f : 0.f;
        float vl = (j > 0) ? 1.f : 0.f;
        float vr = (j < Ww - 1) ? 1.f : 0.f;
        float v[8] = { vt * vl, vt, vt * vr, vl, vr, vb * vl, vb, vb * vr };

        float count = 1.f, s1 = yc;
#pragma unroll
        for (int k = 0; k < 8; ++k) { count += v[k]; s1 += v[k] * yn[k]; }
        float mean = s1 / count;
        float var = (yc - mean) * (yc - mean);
#pragma unroll
        for (int k = 0; k < 8; ++k) { float d = yn[k] - mean; var += v[k] * d * d; }
        var /= count;
        float vs = fmaxf(0.6f * var, 2e-6f);
        float inv_vs = 1.f / vs;

        float wk[8], ws = 0.f;
#pragma unroll
        for (int k = 0; k < 8; ++k) {
            float d = yn[k] - yc;
            wk[k] = v[k] * expf(-d * d * inv_vs);
            ws += wk[k];
        }
        if (mask[i * Ww + j]) {
            out.a = __floats2half2_rn(-0.0f, 0.f);  // sign bit => keep center
        } else {
            float scale = 1.f / ws;
            out.a = __floats2half2_rn(wk[0] * scale, wk[1] * scale);
            out.b = __floats2half2_rn(wk[2] * scale, wk[3] * scale);
            out.c = __floats2half2_rn(wk[4] * scale, wk[5] * scale);
            out.d = __floats2half2_rn(wk[6] * scale, wk[7] * scale);
        }
    }
    w[p] = out;
}

// ---------------------------------------------------------------------------
// iter5p: temporal-tiled register-window stencil, packed fp16 math, now on
// 16x32 tiles with 128-thread blocks -> 2048 blocks = 8 blocks/CU. Same
// waves/CU as before (16) but 8 independent barrier domains per CU: when one
// block's waves stall at a sweep barrier, another block's waves issue.
// Per thread per sweep unchanged: 12 ds_read_b64 + 8 ds_write_b32, 16 hfma2.
// writeRGB!=0 (last launch): fused yiq->rgb epilogue.
// ---------------------------------------------------------------------------
__global__ __launch_bounds__(128, 4)
void iter5p_kernel(const u32* __restrict__ xin, u32* __restrict__ xout,
                   const W8* __restrict__ w, const float* __restrict__ Ypad,
                   float* __restrict__ out, int writeRGB) {
    __shared__ __align__(16) u32 xsm[2][RR * XSH];   // 9.2 KB
    int tid = threadIdx.x;
    int gi0 = blockIdx.y * TR - T;
    int gj0 = blockIdx.x * TC - T;

    // stage x region (half2 px = b32 loads/stores)
#pragma unroll
    for (int k = 0; k < NKS; ++k) {
        int pidx = tid + k * 128;
        if (pidx < NPX) {
            int r = pidx / RC, c = pidx - r * RC;
            xsm[0][r * XSH + c] = xin[(gi0 + r + PO) * PS + (gj0 + c + PO)];
        }
    }

    // 120 active threads, each a 2-wide x 4-tall patch of the 24x40 inner region
    bool active = tid < 120;
    int s  = tid / 20;         // 0..5 -> rows r0 = 1+4s in [1,21]
    int cp = tid - s * 20;     // 0..19 -> cols c0 = 1+2cp in [1,39]
    int r0 = 1 + 4 * s;
    int c0 = 1 + 2 * cp;

    // weights: 8 px/thread, each 8 fp16 duplicated to half2(w,w). 64 u32 regs.
    __half2 wL[4][8], wR[4][8];
    bool keepL[4], keepR[4];
    if (active) {
#pragma unroll
        for (int i = 0; i < 4; ++i) {
            int gp = (gi0 + r0 + i + PO) * PS + (gj0 + c0 + PO);
            W8 wa = w[gp];
            W8 wb = w[gp + 1];
            keepL[i] = (u2(wa.a) & 0x8000u) != 0u;
            keepR[i] = (u2(wb.a) & 0x8000u) != 0u;
            wL[i][0] = __low2half2(wa.a);  wL[i][1] = __high2half2(wa.a);
            wL[i][2] = __low2half2(wa.b);  wL[i][3] = __high2half2(wa.b);
            wL[i][4] = __low2half2(wa.c);  wL[i][5] = __high2half2(wa.c);
            wL[i][6] = __low2half2(wa.d);  wL[i][7] = __high2half2(wa.d);
            wR[i][0] = __low2half2(wb.a);  wR[i][1] = __high2half2(wb.a);
            wR[i][2] = __low2half2(wb.b);  wR[i][3] = __high2half2(wb.b);
            wR[i][4] = __low2half2(wb.c);  wR[i][5] = __high2half2(wb.c);
            wR[i][6] = __low2half2(wb.d);  wR[i][7] = __high2half2(wb.d);
        }
    }
    __syncthreads();

    const __half2 hz = __floats2half2_rn(0.f, 0.f);
    int cur = 0;
#pragma unroll
    for (int t = 1; t <= T; ++t) {
        int nxt = cur ^ 1;
        if (active) {
            // window rows as uint2 pairs: {px c0-1,c0} and {px c0+1,c0+2}
            const uint2* rp;
            uint2 u0, u1, m0, m1;
            rp = (const uint2*)&xsm[cur][(r0 - 1) * XSH]; u0 = rp[cp]; u1 = rp[cp + 1];
            rp = (const uint2*)&xsm[cur][r0 * XSH];       m0 = rp[cp]; m1 = rp[cp + 1];
#pragma unroll
            for (int i = 0; i < 4; ++i) {
                uint2 d0, d1;
                rp = (const uint2*)&xsm[cur][(r0 + i + 1) * XSH];
                d0 = rp[cp]; d1 = rp[cp + 1];

                // left pixel (r0+i, c0): nbrs UL,U,UR,L,R,DL,D,DR
                __half2 accL = keepL[i] ? h2(m0.y) : hz;
                accL = __hfma2(wL[i][0], h2(u0.x), accL);
                accL = __hfma2(wL[i][1], h2(u0.y), accL);
                accL = __hfma2(wL[i][2], h2(u1.x), accL);
                accL = __hfma2(wL[i][3], h2(m0.x), accL);
                accL = __hfma2(wL[i][4], h2(m1.x), accL);
                accL = __hfma2(wL[i][5], h2(d0.x), accL);
                accL = __hfma2(wL[i][6], h2(d0.y), accL);
                accL = __hfma2(wL[i][7], h2(d1.x), accL);

                // right pixel (r0+i, c0+1)
                __half2 accR = keepR[i] ? h2(m1.x) : hz;
                accR = __hfma2(wR[i][0], h2(u0.y), accR);
                accR = __hfma2(wR[i][1], h2(u1.x), accR);
                accR = __hfma2(wR[i][2], h2(u1.y), accR);
                accR = __hfma2(wR[i][3], h2(m0.y), accR);
                accR = __hfma2(wR[i][4], h2(m1.y), accR);
                accR = __hfma2(wR[i][5], h2(d0.y), accR);
                accR = __hfma2(wR[i][6], h2(d1.x), accR);
                accR = __hfma2(wR[i][7], h2(d1.y), accR);

                int wp = (r0 + i) * XSH + c0;
                xsm[nxt][wp]     = u2(accL);
                xsm[nxt][wp + 1] = u2(accR);

                u0 = m0; u1 = m1; m0 = d0; m1 = d1;  // slide window
            }
        }
        __syncthreads();
        cur = nxt;
    }

    if (!writeRGB) {
        // write central 16x32 tile (region rows 5..20, cols 5..36) as half2
#pragma unroll
        for (int k = 0; k < 4; ++k) {
            int pidx = tid + k * 128;          // 0..511
            int r = T + (pidx >> 5), c = T + (pidx & 31);
            xout[(gi0 + r + PO) * PS + (gj0 + c + PO)] = xsm[cur][r * XSH + c];
        }
    } else {
        // fused final: yiq -> rgb, clip, *255 straight from LDS
#pragma unroll
        for (int k = 0; k < 4; ++k) {
            int pidx = tid + k * 128;
            int r = T + (pidx >> 5), c = T + (pidx & 31);
            int gi = gi0 + r, gj = gj0 + c;
            float y = Ypad[(gi + PO) * PS + (gj + PO)];
            u32 pxv = xsm[cur][r * XSH + c];
            float2 iq = __half22float2(h2(pxv));
            float R_ = y + 0.9468822170900693f * iq.x + 0.6235565819861433f * iq.y;
            float G_ = y - 0.27478764629897834f * iq.x - 0.6356910791873801f * iq.y;
            float B_ = y - 1.1085450346420322f * iq.x + 1.7090069284064666f * iq.y;
            int idx = gi * Ww + gj;
            out[idx * 3 + 0] = fminf(fmaxf(R_, 0.f), 1.f) * 255.f;
            out[idx * 3 + 1] = fminf(fmaxf(G_, 0.f), 1.f) * 255.f;
            out[idx * 3 + 2] = fminf(fmaxf(B_, 0.f), 1.f) * 255.f;
        }
    }
}

extern "C" void kernel_launch(void* const* d_in, const int* in_sizes, int n_in,
                              void* d_out, int out_size, void* d_ws, size_t ws_size,
                              hipStream_t stream) {
    const float* gray = (const float*)d_in[0];
    const float* app  = (const float*)d_in[1];
    float* out = (float*)d_out;

    char* ws = (char*)d_ws;
    size_t off = 0;
    auto alloc = [&](size_t bytes) -> void* {
        void* r = ws + off;
        off = (off + bytes + 255) & ~(size_t)255;
        return r;
    };
    float* Ypad = (float*)alloc((size_t)PS * PS * sizeof(float));
    W8*    w    = (W8*)   alloc((size_t)PS * PS * sizeof(W8));
    unsigned char* mask = (unsigned char*)alloc((size_t)Hh * Ww);
    u32*   x0   = (u32*)  alloc((size_t)PS * PS * sizeof(u32));
    u32*   x1   = (u32*)  alloc((size_t)PS * PS * sizeof(u32));

    dim3 blk(64, 4);
    dim3 gridPad((PS + 63) / 64, (PS + 3) / 4);
    prep_kernel<<<gridPad, blk, 0, stream>>>(gray, app, Ypad, x0, x1, mask);
    weights_kernel<<<gridPad, blk, 0, stream>>>(Ypad, mask, w);

    dim3 gridIter(Ww / TC, Hh / TR);  // 32 x 64 = 2048 blocks (8 per CU)
    u32* xin = x0;
    u32* xout = x1;
    for (int l = 0; l < 20; ++l) {    // 20 x 5 = 100 iterations
        int last = (l == 19) ? 1 : 0;
        iter5p_kernel<<<gridIter, 128, 0, stream>>>(xin, xout, w, Ypad, out, last);
        u32* tmp = xin; xin = xout; xout = tmp;
    }
}

// Round 11
// 302.334 us; speedup vs baseline: 1.0605x; 1.0605x over previous
//
#include <hip/hip_runtime.h>
#include <hip/hip_fp16.h>

#define Hh 1024
#define Ww 1024
#define PO 12        // halo offset (>= T+2)
#define PS 1048      // padded row stride = 1024 + 2*PO
#define T 10         // fused iterations per launch (100 = 10 launches x 10)
#define TILE 32      // output tile per block
#define RG 52        // region = TILE + 2T
#define XSH 54       // LDS row stride in px (half2 = 4B; EVEN -> uint2 aligned)
#define NPX (RG * RG)  // 2704 region pixels
#define NK 11        // ceil(NPX / 256)

typedef unsigned int u32;

// packed per-pixel weights: 8 x fp16 in one 16B struct (w0..w7)
struct alignas(16) W8 { __half2 a, b, c, d; };

__device__ inline __half2 h2(u32 v) { return *(__half2*)&v; }
__device__ inline u32 u2(__half2 v) { return *(u32*)&v; }

// ---------------------------------------------------------------------------
// prep: Ypad (luma, zero halo), x0 = b as half2 (IQ if colored else 0, zero
// halo), x1 = 0, mask (isColored).
// ---------------------------------------------------------------------------
__global__ __launch_bounds__(256)
void prep_kernel(const float* __restrict__ gray, const float* __restrict__ app,
                 float* __restrict__ Ypad, u32* __restrict__ x0,
                 u32* __restrict__ x1, unsigned char* __restrict__ mask) {
    int px = blockIdx.x * 64 + threadIdx.x;
    int py = blockIdx.y * 4 + threadIdx.y;
    if (px >= PS || py >= PS) return;
    int p = py * PS + px;
    int i = py - PO, j = px - PO;
    float yv = 0.f;
    float2 bv = make_float2(0.f, 0.f);
    if (i >= 0 && i < Hh && j >= 0 && j < Ww) {
        int idx = i * Ww + j;
        const float s = 1.f / 255.f;
        float gr = gray[idx * 3 + 0] * s;
        float gg = gray[idx * 3 + 1] * s;
        float gb = gray[idx * 3 + 2] * s;
        float ar = app[idx * 3 + 0] * s;
        float ag = app[idx * 3 + 1] * s;
        float ab = app[idx * 3 + 2] * s;
        float diff = fabsf(gr - ar) + fabsf(gg - ag) + fabsf(gb - ab);
        bool colored = diff > 0.01f;
        yv = 0.3f * gr + 0.59f * gg + 0.11f * gb;
        float ay = 0.3f * ar + 0.59f * ag + 0.11f * ab;
        float ai = 0.74f * (ar - ay) - 0.27f * (ab - ay);
        float aq = 0.48f * (ar - ay) + 0.41f * (ab - ay);
        if (colored) bv = make_float2(ai, aq);
        mask[idx] = colored ? 1 : 0;
    }
    Ypad[p] = yv;
    __half2 h = __floats2half2_rn(bv.x, bv.y);
    x0[p] = u2(h);
    x1[p] = 0u;                 // half2(0,0)
}

// ---------------------------------------------------------------------------
// weights: per padded pixel, 8 normalized neighbor weights packed fp16 (16B).
// Outside the image: all zero. Colored pixel: all zero except sign bit on w0
// (-0.0h = "keep center").
// ---------------------------------------------------------------------------
__global__ __launch_bounds__(256)
void weights_kernel(const float* __restrict__ Ypad,
                    const unsigned char* __restrict__ mask,
                    W8* __restrict__ w) {
    int px = blockIdx.x * 64 + threadIdx.x;
    int py = blockIdx.y * 4 + threadIdx.y;
    if (px >= PS || py >= PS) return;
    int p = py * PS + px;
    int i = py - PO, j = px - PO;
    W8 out;
    out.a = __floats2half2_rn(0.f, 0.f);
    out.b = out.a; out.c = out.a; out.d = out.a;
    if (i >= 0 && i < Hh && j >= 0 && j < Ww) {
        float yc = Ypad[p];
        float yn[8];
        yn[0] = Ypad[p - PS - 1]; yn[1] = Ypad[p - PS]; yn[2] = Ypad[p - PS + 1];
        yn[3] = Ypad[p - 1];                            yn[4] = Ypad[p + 1];
        yn[5] = Ypad[p + PS - 1]; yn[6] = Ypad[p + PS]; yn[7] = Ypad[p + PS + 1];
        float vt = (i > 0) ? 1.f : 0.f;
        float vb = (i < Hh - 1) ? 1.f : 0.f;
        float vl = (j > 0) ? 1.f : 0.f;
        float vr = (j < Ww - 1) ? 1.f : 0.f;
        float v[8] = { vt * vl, vt, vt * vr, vl, vr, vb * vl, vb, vb * vr };

        float count = 1.f, s1 = yc;
#pragma unroll
        for (int k = 0; k < 8; ++k) { count += v[k]; s1 += v[k] * yn[k]; }
        float mean = s1 / count;
        float var = (yc - mean) * (yc - mean);
#pragma unroll
        for (int k = 0; k < 8; ++k) { float d = yn[k] - mean; var += v[k] * d * d; }
        var /= count;
        float vs = fmaxf(0.6f * var, 2e-6f);
        float inv_vs = 1.f / vs;

        float wk[8], ws = 0.f;
#pragma unroll
        for (int k = 0; k < 8; ++k) {
            float d = yn[k] - yc;
            wk[k] = v[k] * expf(-d * d * inv_vs);
            ws += wk[k];
        }
        if (mask[i * Ww + j]) {
            out.a = __floats2half2_rn(-0.0f, 0.f);  // sign bit => keep center
        } else {
            float scale = 1.f / ws;
            out.a = __floats2half2_rn(wk[0] * scale, wk[1] * scale);
            out.b = __floats2half2_rn(wk[2] * scale, wk[3] * scale);
            out.c = __floats2half2_rn(wk[4] * scale, wk[5] * scale);
            out.d = __floats2half2_rn(wk[6] * scale, wk[7] * scale);
        }
    }
    w[p] = out;
}

// ---------------------------------------------------------------------------
// iter10p: T=10 temporal-tiled register-window stencil, packed fp16 math.
// 52x52 region in LDS (22.5 KB ping-pong), 250 active threads each own a
// 2-wide x 5-tall patch of the 50x50 inner region; weights (10 px x 8 half2
// = 80 VGPRs) resident across all 10 sweeps. Full inner region computed
// every sweep (no guards): garbage front (rim) advances 1 px/sweep, validity
// front shrinks 1 px/sweep, margins meet exactly at the central 32x32 tile.
// writeRGB!=0 (last launch): fused yiq->rgb epilogue.
// ---------------------------------------------------------------------------
__global__ __launch_bounds__(256, 4)
void iter10p_kernel(const u32* __restrict__ xin, u32* __restrict__ xout,
                    const W8* __restrict__ w, const float* __restrict__ Ypad,
                    float* __restrict__ out, int writeRGB) {
    __shared__ __align__(16) u32 xsm[2][RG * XSH];   // 22.5 KB
    int tid = threadIdx.x;
    int gi0 = blockIdx.y * TILE - T;
    int gj0 = blockIdx.x * TILE - T;

    // stage x region (half2 px = b32 loads/stores)
#pragma unroll
    for (int k = 0; k < NK; ++k) {
        int pidx = tid + k * 256;
        if (pidx < NPX) {
            int r = pidx / RG, c = pidx - r * RG;
            xsm[0][r * XSH + c] = xin[(gi0 + r + PO) * PS + (gj0 + c + PO)];
        }
    }

    // 250 active threads: strip s = tid/25 -> rows r0=1+5s..r0+4 (in [1,50]);
    // cp = tid%25 -> cols c0=1+2cp, c0+1 (c0 odd => c0-1 even, uint2 aligned)
    bool active = tid < 250;
    int s  = tid / 25;
    int cp = tid - s * 25;
    int r0 = 1 + 5 * s;
    int c0 = 1 + 2 * cp;

    // weights: 10 px/thread, each 8 fp16 duplicated to half2(w,w). 80 u32 regs.
    __half2 wL[5][8], wR[5][8];
    if (active) {
#pragma unroll
        for (int i = 0; i < 5; ++i) {
            int gp = (gi0 + r0 + i + PO) * PS + (gj0 + c0 + PO);
            W8 wa = w[gp];
            W8 wb = w[gp + 1];
            wL[i][0] = __low2half2(wa.a);  wL[i][1] = __high2half2(wa.a);
            wL[i][2] = __low2half2(wa.b);  wL[i][3] = __high2half2(wa.b);
            wL[i][4] = __low2half2(wa.c);  wL[i][5] = __high2half2(wa.c);
            wL[i][6] = __low2half2(wa.d);  wL[i][7] = __high2half2(wa.d);
            wR[i][0] = __low2half2(wb.a);  wR[i][1] = __high2half2(wb.a);
            wR[i][2] = __low2half2(wb.b);  wR[i][3] = __high2half2(wb.b);
            wR[i][4] = __low2half2(wb.c);  wR[i][5] = __high2half2(wb.c);
            wR[i][6] = __low2half2(wb.d);  wR[i][7] = __high2half2(wb.d);
        }
    }
    __syncthreads();

    int cur = 0;
#pragma unroll 1
    for (int t = 0; t < T; ++t) {        // rolled: no t-dependence inside
        int nxt = cur ^ 1;
        if (active) {
            const uint2* rp;
            uint2 u0, u1, m0, m1;
            rp = (const uint2*)&xsm[cur][(r0 - 1) * XSH]; u0 = rp[cp]; u1 = rp[cp + 1];
            rp = (const uint2*)&xsm[cur][r0 * XSH];       m0 = rp[cp]; m1 = rp[cp + 1];
#pragma unroll
            for (int i = 0; i < 5; ++i) {
                uint2 d0, d1;
                rp = (const uint2*)&xsm[cur][(r0 + i + 1) * XSH];
                d0 = rp[cp]; d1 = rp[cp + 1];

                // keep flags recomputed from sign bit (saves registers)
                __half2 hz = __floats2half2_rn(0.f, 0.f);
                __half2 accL = (u2(wL[i][0]) & 0x8000u) ? h2(m0.y) : hz;
                accL = __hfma2(wL[i][0], h2(u0.x), accL);
                accL = __hfma2(wL[i][1], h2(u0.y), accL);
                accL = __hfma2(wL[i][2], h2(u1.x), accL);
                accL = __hfma2(wL[i][3], h2(m0.x), accL);
                accL = __hfma2(wL[i][4], h2(m1.x), accL);
                accL = __hfma2(wL[i][5], h2(d0.x), accL);
                accL = __hfma2(wL[i][6], h2(d0.y), accL);
                accL = __hfma2(wL[i][7], h2(d1.x), accL);

                __half2 accR = (u2(wR[i][0]) & 0x8000u) ? h2(m1.x) : hz;
                accR = __hfma2(wR[i][0], h2(u0.y), accR);
                accR = __hfma2(wR[i][1], h2(u1.x), accR);
                accR = __hfma2(wR[i][2], h2(u1.y), accR);
                accR = __hfma2(wR[i][3], h2(m0.y), accR);
                accR = __hfma2(wR[i][4], h2(m1.y), accR);
                accR = __hfma2(wR[i][5], h2(d0.y), accR);
                accR = __hfma2(wR[i][6], h2(d1.x), accR);
                accR = __hfma2(wR[i][7], h2(d1.y), accR);

                int wp = (r0 + i) * XSH + c0;
                xsm[nxt][wp]     = u2(accL);
                xsm[nxt][wp + 1] = u2(accR);

                u0 = m0; u1 = m1; m0 = d0; m1 = d1;  // slide window
            }
        }
        __syncthreads();
        cur = nxt;
    }

    if (!writeRGB) {
        // write central 32x32 tile (region rows/cols 10..41) as half2
#pragma unroll
        for (int k = 0; k < 4; ++k) {
            int pidx = tid + k * 256;
            int r = T + (pidx >> 5), c = T + (pidx & 31);
            xout[(gi0 + r + PO) * PS + (gj0 + c + PO)] = xsm[cur][r * XSH + c];
        }
    } else {
        // fused final: yiq -> rgb, clip, *255 straight from LDS
#pragma unroll
        for (int k = 0; k < 4; ++k) {
            int pidx = tid + k * 256;
            int r = T + (pidx >> 5), c = T + (pidx & 31);
            int gi = gi0 + r, gj = gj0 + c;
            float y = Ypad[(gi + PO) * PS + (gj + PO)];
            u32 pxv = xsm[cur][r * XSH + c];
            float2 iq = __half22float2(h2(pxv));
            float R_ = y + 0.9468822170900693f * iq.x + 0.6235565819861433f * iq.y;
            float G_ = y - 0.27478764629897834f * iq.x - 0.6356910791873801f * iq.y;
            float B_ = y - 1.1085450346420322f * iq.x + 1.7090069284064666f * iq.y;
            int idx = gi * Ww + gj;
            out[idx * 3 + 0] = fminf(fmaxf(R_, 0.f), 1.f) * 255.f;
            out[idx * 3 + 1] = fminf(fmaxf(G_, 0.f), 1.f) * 255.f;
            out[idx * 3 + 2] = fminf(fmaxf(B_, 0.f), 1.f) * 255.f;
        }
    }
}

extern "C" void kernel_launch(void* const* d_in, const int* in_sizes, int n_in,
                              void* d_out, int out_size, void* d_ws, size_t ws_size,
                              hipStream_t stream) {
    const float* gray = (const float*)d_in[0];
    const float* app  = (const float*)d_in[1];
    float* out = (float*)d_out;

    char* ws = (char*)d_ws;
    size_t off = 0;
    auto alloc = [&](size_t bytes) -> void* {
        void* r = ws + off;
        off = (off + bytes + 255) & ~(size_t)255;
        return r;
    };
    float* Ypad = (float*)alloc((size_t)PS * PS * sizeof(float));
    W8*    w    = (W8*)   alloc((size_t)PS * PS * sizeof(W8));
    unsigned char* mask = (unsigned char*)alloc((size_t)Hh * Ww);
    u32*   x0   = (u32*)  alloc((size_t)PS * PS * sizeof(u32));
    u32*   x1   = (u32*)  alloc((size_t)PS * PS * sizeof(u32));

    dim3 blk(64, 4);
    dim3 gridPad((PS + 63) / 64, (PS + 3) / 4);
    prep_kernel<<<gridPad, blk, 0, stream>>>(gray, app, Ypad, x0, x1, mask);
    weights_kernel<<<gridPad, blk, 0, stream>>>(Ypad, mask, w);

    dim3 gridIter(Ww / TILE, Hh / TILE);  // 32 x 32 = 1024 blocks (4 per CU)
    u32* xin = x0;
    u32* xout = x1;
    for (int l = 0; l < 10; ++l) {        // 10 x 10 = 100 iterations
        int last = (l == 9) ? 1 : 0;
        iter10p_kernel<<<gridIter, 256, 0, stream>>>(xin, xout, w, Ypad, out, last);
        u32* tmp = xin; xin = xout; xout = tmp;
    }
}

// Round 12
// 292.549 us; speedup vs baseline: 1.0960x; 1.0334x over previous
//
#include <hip/hip_runtime.h>
#include <hip/hip_fp16.h>

#define Hh 1024
#define Ww 1024
#define PO 12        // halo offset (>= T+2)
#define PS 1048      // padded row stride = 1024 + 2*PO
#define T 10         // fused iterations per launch (100 = 10 launches x 10)
#define TILE 32      // output tile per block
#define RG 52        // region = TILE + 2T
#define XSH 54       // LDS row stride in px (half2 = 4B; EVEN -> uint2 aligned)
#define NPX (RG * RG)  // 2704 region pixels

typedef unsigned int u32;

// packed per-pixel weights: 8 x fp16 in one 16B struct (w0..w7)
struct alignas(16) W8 { __half2 a, b, c, d; };

__device__ inline __half2 h2(u32 v) { return *(__half2*)&v; }
__device__ inline u32 u2(__half2 v) { return *(u32*)&v; }

// address-space typedefs for global_load_lds (async global->LDS DMA)
typedef __attribute__((address_space(3))) u32 lds_u32_t;
typedef __attribute__((address_space(1))) const u32 glb_u32_t;

// ---------------------------------------------------------------------------
// prep: Ypad (luma, zero halo), x0 = b as half2 (IQ if colored else 0, zero
// halo), x1 = 0, mask (isColored).
// ---------------------------------------------------------------------------
__global__ __launch_bounds__(256)
void prep_kernel(const float* __restrict__ gray, const float* __restrict__ app,
                 float* __restrict__ Ypad, u32* __restrict__ x0,
                 u32* __restrict__ x1, unsigned char* __restrict__ mask) {
    int px = blockIdx.x * 64 + threadIdx.x;
    int py = blockIdx.y * 4 + threadIdx.y;
    if (px >= PS || py >= PS) return;
    int p = py * PS + px;
    int i = py - PO, j = px - PO;
    float yv = 0.f;
    float2 bv = make_float2(0.f, 0.f);
    if (i >= 0 && i < Hh && j >= 0 && j < Ww) {
        int idx = i * Ww + j;
        const float s = 1.f / 255.f;
        float gr = gray[idx * 3 + 0] * s;
        float gg = gray[idx * 3 + 1] * s;
        float gb = gray[idx * 3 + 2] * s;
        float ar = app[idx * 3 + 0] * s;
        float ag = app[idx * 3 + 1] * s;
        float ab = app[idx * 3 + 2] * s;
        float diff = fabsf(gr - ar) + fabsf(gg - ag) + fabsf(gb - ab);
        bool colored = diff > 0.01f;
        yv = 0.3f * gr + 0.59f * gg + 0.11f * gb;
        float ay = 0.3f * ar + 0.59f * ag + 0.11f * ab;
        float ai = 0.74f * (ar - ay) - 0.27f * (ab - ay);
        float aq = 0.48f * (ar - ay) + 0.41f * (ab - ay);
        if (colored) bv = make_float2(ai, aq);
        mask[idx] = colored ? 1 : 0;
    }
    Ypad[p] = yv;
    __half2 h = __floats2half2_rn(bv.x, bv.y);
    x0[p] = u2(h);
    x1[p] = 0u;                 // half2(0,0)
}

// ---------------------------------------------------------------------------
// weights: per padded pixel, 8 normalized neighbor weights packed fp16 (16B).
// Outside the image: all zero. Colored pixel: all zero except sign bit on w0
// (-0.0h = "keep center").
// ---------------------------------------------------------------------------
__global__ __launch_bounds__(256)
void weights_kernel(const float* __restrict__ Ypad,
                    const unsigned char* __restrict__ mask,
                    W8* __restrict__ w) {
    int px = blockIdx.x * 64 + threadIdx.x;
    int py = blockIdx.y * 4 + threadIdx.y;
    if (px >= PS || py >= PS) return;
    int p = py * PS + px;
    int i = py - PO, j = px - PO;
    W8 out;
    out.a = __floats2half2_rn(0.f, 0.f);
    out.b = out.a; out.c = out.a; out.d = out.a;
    if (i >= 0 && i < Hh && j >= 0 && j < Ww) {
        float yc = Ypad[p];
        float yn[8];
        yn[0] = Ypad[p - PS - 1]; yn[1] = Ypad[p - PS]; yn[2] = Ypad[p - PS + 1];
        yn[3] = Ypad[p - 1];                            yn[4] = Ypad[p + 1];
        yn[5] = Ypad[p + PS - 1]; yn[6] = Ypad[p + PS]; yn[7] = Ypad[p + PS + 1];
        float vt = (i > 0) ? 1.f : 0.f;
        float vb = (i < Hh - 1) ? 1.f : 0.f;
        float vl = (j > 0) ? 1.f : 0.f;
        float vr = (j < Ww - 1) ? 1.f : 0.f;
        float v[8] = { vt * vl, vt, vt * vr, vl, vr, vb * vl, vb, vb * vr };

        float count = 1.f, s1 = yc;
#pragma unroll
        for (int k = 0; k < 8; ++k) { count += v[k]; s1 += v[k] * yn[k]; }
        float mean = s1 / count;
        float var = (yc - mean) * (yc - mean);
#pragma unroll
        for (int k = 0; k < 8; ++k) { float d = yn[k] - mean; var += v[k] * d * d; }
        var /= count;
        float vs = fmaxf(0.6f * var, 2e-6f);
        float inv_vs = 1.f / vs;

        float wk[8], ws = 0.f;
#pragma unroll
        for (int k = 0; k < 8; ++k) {
            float d = yn[k] - yc;
            wk[k] = v[k] * expf(-d * d * inv_vs);
            ws += wk[k];
        }
        if (mask[i * Ww + j]) {
            out.a = __floats2half2_rn(-0.0f, 0.f);  // sign bit => keep center
        } else {
            float scale = 1.f / ws;
            out.a = __floats2half2_rn(wk[0] * scale, wk[1] * scale);
            out.b = __floats2half2_rn(wk[2] * scale, wk[3] * scale);
            out.c = __floats2half2_rn(wk[4] * scale, wk[5] * scale);
            out.d = __floats2half2_rn(wk[6] * scale, wk[7] * scale);
        }
    }
    w[p] = out;
}

// ---------------------------------------------------------------------------
// iter10p: T=10 temporal-tiled register-window stencil, packed fp16 math.
// R12 change: staging now uses async global_load_lds DMA (width 4) — lanes
// 0..51 of each wave carry one px of a region row, 13 rows per wave; no VGPR
// round-trip, no per-px address math; the weight VMEM loads issue behind the
// in-flight DMA and one barrier drains both. Inner loop bit-identical to R11.
// ---------------------------------------------------------------------------
__global__ __launch_bounds__(256, 4)
void iter10p_kernel(const u32* __restrict__ xin, u32* __restrict__ xout,
                    const W8* __restrict__ w, const float* __restrict__ Ypad,
                    float* __restrict__ out, int writeRGB) {
    __shared__ __align__(16) u32 xsm[2][RG * XSH];   // 22.5 KB
    int tid = threadIdx.x;
    int gi0 = blockIdx.y * TILE - T;
    int gj0 = blockIdx.x * TILE - T;

    // async stage: wave wv stages rows wv*13 .. wv*13+12; lane ln carries px ln
    {
        int wv = tid >> 6;
        int ln = tid & 63;
        if (ln < RG) {
            const u32* gbase = xin + (size_t)(gi0 + wv * 13 + PO) * PS + (gj0 + PO) + ln;
#pragma unroll 1
            for (int k = 0; k < 13; ++k) {
                __builtin_amdgcn_global_load_lds((glb_u32_t*)(gbase + (size_t)k * PS),
                                                 (lds_u32_t*)&xsm[0][(wv * 13 + k) * XSH],
                                                 4, 0, 0);
            }
        }
    }

    // 250 active threads: strip s = tid/25 -> rows r0=1+5s..r0+4 (in [1,50]);
    // cp = tid%25 -> cols c0=1+2cp, c0+1 (c0 odd => c0-1 even, uint2 aligned)
    bool active = tid < 250;
    int s  = tid / 25;
    int cp = tid - s * 25;
    int r0 = 1 + 5 * s;
    int c0 = 1 + 2 * cp;

    // weights: 10 px/thread, each 8 fp16 duplicated to half2(w,w). 80 u32 regs.
    // These VMEM loads overlap the staging DMA above.
    __half2 wL[5][8], wR[5][8];
    if (active) {
#pragma unroll
        for (int i = 0; i < 5; ++i) {
            int gp = (gi0 + r0 + i + PO) * PS + (gj0 + c0 + PO);
            W8 wa = w[gp];
            W8 wb = w[gp + 1];
            wL[i][0] = __low2half2(wa.a);  wL[i][1] = __high2half2(wa.a);
            wL[i][2] = __low2half2(wa.b);  wL[i][3] = __high2half2(wa.b);
            wL[i][4] = __low2half2(wa.c);  wL[i][5] = __high2half2(wa.c);
            wL[i][6] = __low2half2(wa.d);  wL[i][7] = __high2half2(wa.d);
            wR[i][0] = __low2half2(wb.a);  wR[i][1] = __high2half2(wb.a);
            wR[i][2] = __low2half2(wb.b);  wR[i][3] = __high2half2(wb.b);
            wR[i][4] = __low2half2(wb.c);  wR[i][5] = __high2half2(wb.c);
            wR[i][6] = __low2half2(wb.d);  wR[i][7] = __high2half2(wb.d);
        }
    }
    __syncthreads();   // drains the DMA (vmcnt) + makes staged region visible

    int cur = 0;
#pragma unroll 1
    for (int t = 0; t < T; ++t) {        // rolled: no t-dependence inside
        int nxt = cur ^ 1;
        if (active) {
            const uint2* rp;
            uint2 u0, u1, m0, m1;
            rp = (const uint2*)&xsm[cur][(r0 - 1) * XSH]; u0 = rp[cp]; u1 = rp[cp + 1];
            rp = (const uint2*)&xsm[cur][r0 * XSH];       m0 = rp[cp]; m1 = rp[cp + 1];
#pragma unroll
            for (int i = 0; i < 5; ++i) {
                uint2 d0, d1;
                rp = (const uint2*)&xsm[cur][(r0 + i + 1) * XSH];
                d0 = rp[cp]; d1 = rp[cp + 1];

                // keep flags recomputed from sign bit (saves registers)
                __half2 hz = __floats2half2_rn(0.f, 0.f);
                __half2 accL = (u2(wL[i][0]) & 0x8000u) ? h2(m0.y) : hz;
                accL = __hfma2(wL[i][0], h2(u0.x), accL);
                accL = __hfma2(wL[i][1], h2(u0.y), accL);
                accL = __hfma2(wL[i][2], h2(u1.x), accL);
                accL = __hfma2(wL[i][3], h2(m0.x), accL);
                accL = __hfma2(wL[i][4], h2(m1.x), accL);
                accL = __hfma2(wL[i][5], h2(d0.x), accL);
                accL = __hfma2(wL[i][6], h2(d0.y), accL);
                accL = __hfma2(wL[i][7], h2(d1.x), accL);

                __half2 accR = (u2(wR[i][0]) & 0x8000u) ? h2(m1.x) : hz;
                accR = __hfma2(wR[i][0], h2(u0.y), accR);
                accR = __hfma2(wR[i][1], h2(u1.x), accR);
                accR = __hfma2(wR[i][2], h2(u1.y), accR);
                accR = __hfma2(wR[i][3], h2(m0.y), accR);
                accR = __hfma2(wR[i][4], h2(m1.y), accR);
                accR = __hfma2(wR[i][5], h2(d0.y), accR);
                accR = __hfma2(wR[i][6], h2(d1.x), accR);
                accR = __hfma2(wR[i][7], h2(d1.y), accR);

                int wp = (r0 + i) * XSH + c0;
                xsm[nxt][wp]     = u2(accL);
                xsm[nxt][wp + 1] = u2(accR);

                u0 = m0; u1 = m1; m0 = d0; m1 = d1;  // slide window
            }
        }
        __syncthreads();
        cur = nxt;
    }

    if (!writeRGB) {
        // write central 32x32 tile (region rows/cols 10..41) as half2
#pragma unroll
        for (int k = 0; k < 4; ++k) {
            int pidx = tid + k * 256;
            int r = T + (pidx >> 5), c = T + (pidx & 31);
            xout[(gi0 + r + PO) * PS + (gj0 + c + PO)] = xsm[cur][r * XSH + c];
        }
    } else {
        // fused final: yiq -> rgb, clip, *255 straight from LDS
#pragma unroll
        for (int k = 0; k < 4; ++k) {
            int pidx = tid + k * 256;
            int r = T + (pidx >> 5), c = T + (pidx & 31);
            int gi = gi0 + r, gj = gj0 + c;
            float y = Ypad[(gi + PO) * PS + (gj + PO)];
            u32 pxv = xsm[cur][r * XSH + c];
            float2 iq = __half22float2(h2(pxv));
            float R_ = y + 0.9468822170900693f * iq.x + 0.6235565819861433f * iq.y;
            float G_ = y - 0.27478764629897834f * iq.x - 0.6356910791873801f * iq.y;
            float B_ = y - 1.1085450346420322f * iq.x + 1.7090069284064666f * iq.y;
            int idx = gi * Ww + gj;
            out[idx * 3 + 0] = fminf(fmaxf(R_, 0.f), 1.f) * 255.f;
            out[idx * 3 + 1] = fminf(fmaxf(G_, 0.f), 1.f) * 255.f;
            out[idx * 3 + 2] = fminf(fmaxf(B_, 0.f), 1.f) * 255.f;
        }
    }
}

extern "C" void kernel_launch(void* const* d_in, const int* in_sizes, int n_in,
                              void* d_out, int out_size, void* d_ws, size_t ws_size,
                              hipStream_t stream) {
    const float* gray = (const float*)d_in[0];
    const float* app  = (const float*)d_in[1];
    float* out = (float*)d_out;

    char* ws = (char*)d_ws;
    size_t off = 0;
    auto alloc = [&](size_t bytes) -> void* {
        void* r = ws + off;
        off = (off + bytes + 255) & ~(size_t)255;
        return r;
    };
    float* Ypad = (float*)alloc((size_t)PS * PS * sizeof(float));
    W8*    w    = (W8*)   alloc((size_t)PS * PS * sizeof(W8));
    unsigned char* mask = (unsigned char*)alloc((size_t)Hh * Ww);
    u32*   x0   = (u32*)  alloc((size_t)PS * PS * sizeof(u32));
    u32*   x1   = (u32*)  alloc((size_t)PS * PS * sizeof(u32));

    dim3 blk(64, 4);
    dim3 gridPad((PS + 63) / 64, (PS + 3) / 4);
    prep_kernel<<<gridPad, blk, 0, stream>>>(gray, app, Ypad, x0, x1, mask);
    weights_kernel<<<gridPad, blk, 0, stream>>>(Ypad, mask, w);

    dim3 gridIter(Ww / TILE, Hh / TILE);  // 32 x 32 = 1024 blocks (4 per CU)
    u32* xin = x0;
    u32* xout = x1;
    for (int l = 0; l < 10; ++l) {        // 10 x 10 = 100 iterations
        int last = (l == 9) ? 1 : 0;
        iter10p_kernel<<<gridIter, 256, 0, stream>>>(xin, xout, w, Ypad, out, last);
        u32* tmp = xin; xin = xout; xout = tmp;
    }
}